// Round 7
// baseline (230.577 us; speedup 1.0000x reference)
//
#include <hip/hip_runtime.h>
#include <hip/hip_bf16.h>

typedef __attribute__((ext_vector_type(8))) __bf16 bf16x8;
typedef __attribute__((ext_vector_type(4))) __bf16 bf16x4;
typedef __attribute__((ext_vector_type(4))) float f32x4;

#define T_SEQ   2048
#define DMODEL  1024

__device__ __forceinline__ void gload_lds16(const void* g, void* l) {
  __builtin_amdgcn_global_load_lds((const __attribute__((address_space(1))) void*)g,
                                   (__attribute__((address_space(3))) void*)l, 16, 0, 0);
}
#define VMCNT0() asm volatile("s_waitcnt vmcnt(0)" ::: "memory")

// ---------------- f32 -> bf16 convert (vectorized) ----------------
__global__ __launch_bounds__(256) void f32_to_bf16_k(const float* __restrict__ s,
                                                     __bf16* __restrict__ d, int n) {
  int i = (blockIdx.x * 256 + threadIdx.x) * 8;
  if (i >= n) return;
  float4 a = *(const float4*)(s + i);
  float4 b = *(const float4*)(s + i + 4);
  bf16x8 o;
  o[0] = (__bf16)a.x; o[1] = (__bf16)a.y; o[2] = (__bf16)a.z; o[3] = (__bf16)a.w;
  o[4] = (__bf16)b.x; o[5] = (__bf16)b.y; o[6] = (__bf16)b.z; o[7] = (__bf16)b.w;
  *(bf16x8*)(d + i) = o;
}

// fused weight converts: Wq,Wk,Wv -> wqkv (3M), Wo -> wob (1M)
__global__ __launch_bounds__(256) void w_to_bf16_k(const float* __restrict__ Wq,
                                                   const float* __restrict__ Wk,
                                                   const float* __restrict__ Wv,
                                                   const float* __restrict__ Wo,
                                                   __bf16* __restrict__ wqkv,
                                                   __bf16* __restrict__ wob) {
  int i = (blockIdx.x * 256 + threadIdx.x) * 8;   // 0..4M
  int sec = i >> 20, o = i & 1048575;
  const float* s = (sec == 0) ? Wq : (sec == 1) ? Wk : (sec == 2) ? Wv : Wo;
  __bf16* d = (sec == 3) ? (wob + o) : (wqkv + i);
  float4 a = *(const float4*)(s + o);
  float4 b = *(const float4*)(s + o + 4);
  bf16x8 v;
  v[0] = (__bf16)a.x; v[1] = (__bf16)a.y; v[2] = (__bf16)a.z; v[3] = (__bf16)a.w;
  v[4] = (__bf16)b.x; v[5] = (__bf16)b.y; v[6] = (__bf16)b.z; v[7] = (__bf16)b.w;
  *(bf16x8*)d = v;
}

// ---------------- RoPE table, [j][t] layout: tbl[j*T + t] = (cos, sin) -----
__global__ __launch_bounds__(256) void rope_table_k(const int* __restrict__ pos,
                                                    float2* __restrict__ tbl) {
  int idx = blockIdx.x * 256 + threadIdx.x;  // 32*T
  int j = idx >> 11, t = idx & 2047;
  float p = (float)pos[t];
  float inv = powf(10000.0f, -(float)j * (1.0f / 32.0f));
  float a = p * inv;
  tbl[idx] = make_float2(cosf(a), sinf(a));
}

// ---------------- generic GEMM: C(M,N) = A(M,K) @ W(N,K)^T (for Wo) --------
// 1D grid, XCD-chunked swizzle, double-buffered LDS prefetch.
template <typename OutT>
__global__ __launch_bounds__(256) void gemm_bt(const __bf16* __restrict__ A,
                                               const __bf16* __restrict__ W,
                                               OutT* __restrict__ C,
                                               int M, int N, int K) {
  __shared__ alignas(16) __bf16 At[2][128 * 32];
  __shared__ alignas(16) __bf16 Bt[2][128 * 32];
  const int tid = threadIdx.x, w = tid >> 6, l = tid & 63;
  const int l16 = l & 15, lq = l >> 4;
  const int wm = w >> 1, wn = w & 1;
  const int nwg = gridDim.x, chunk = nwg >> 3, f = blockIdx.x;
  const int swz = (f & 7) * chunk + (f >> 3);
  const int nx = N >> 7;
  const int br = (swz / nx) * 128, bc = (swz % nx) * 128;
  f32x4 acc[4][4] = {};
  const int off = w * 1024 + l * 16;
  const int rA = off >> 6, cA = off & 63;

  auto stage = [&](int bufi, int kt) {
    gload_lds16((const char*)A + ((size_t)(br + rA) * K + kt) * 2 + cA,
                (char*)(&At[bufi][0]) + w * 1024);
    gload_lds16((const char*)A + ((size_t)(br + 64 + rA) * K + kt) * 2 + cA,
                (char*)(&At[bufi][0]) + 4096 + w * 1024);
    gload_lds16((const char*)W + ((size_t)(bc + rA) * K + kt) * 2 + cA,
                (char*)(&Bt[bufi][0]) + w * 1024);
    gload_lds16((const char*)W + ((size_t)(bc + 64 + rA) * K + kt) * 2 + cA,
                (char*)(&Bt[bufi][0]) + 4096 + w * 1024);
  };

  stage(0, 0);
  VMCNT0();
  __builtin_amdgcn_s_barrier();

  const int nkt = K >> 5;
  int buf = 0;
  for (int i = 0; i < nkt; ++i) {
    if (i + 1 < nkt) stage(buf ^ 1, (i + 1) << 5);

    bf16x8 af[4], bfr[4];
#pragma unroll
    for (int m = 0; m < 4; ++m)
      af[m] = *(const bf16x8*)(&At[buf][0] + (wm * 64 + m * 16 + l16) * 32 + lq * 8);
#pragma unroll
    for (int n = 0; n < 4; ++n)
      bfr[n] = *(const bf16x8*)(&Bt[buf][0] + (wn * 64 + n * 16 + l16) * 32 + lq * 8);
    __builtin_amdgcn_s_setprio(1);
#pragma unroll
    for (int m = 0; m < 4; ++m)
#pragma unroll
      for (int n = 0; n < 4; ++n)
        acc[m][n] = __builtin_amdgcn_mfma_f32_16x16x32_bf16(af[m], bfr[n], acc[m][n], 0, 0, 0);
    __builtin_amdgcn_s_setprio(0);

    VMCNT0();
    __builtin_amdgcn_s_barrier();
    buf ^= 1;
  }

#pragma unroll
  for (int m = 0; m < 4; ++m)
#pragma unroll
    for (int n = 0; n < 4; ++n)
#pragma unroll
      for (int r = 0; r < 4; ++r) {
        int row = br + wm * 64 + m * 16 + lq * 4 + r;
        int col = bc + wn * 64 + n * 16 + l16;
        float v = acc[m][n][r];
        if constexpr (__is_same(OutT, float))
          C[(size_t)row * N + col] = v;
        else
          C[(size_t)row * N + col] = (__bf16)v;
      }
}

// ---------------- fused QKV GEMM (operand-swapped) + RoPE epilogue ----------
// 1D grid 768, XCD swizzle, dbuf prefetch. Lane holds 4 consecutive d.
// q (scaled 1/8) and k: rope in-lane, 8B stores to (B,H,T,64). v: (B,H,64,T).
__global__ __launch_bounds__(256) void gemm_qkv_k(const __bf16* __restrict__ A,
                                                  const __bf16* __restrict__ W,
                                                  __bf16* __restrict__ qr,
                                                  __bf16* __restrict__ kr,
                                                  __bf16* __restrict__ vt,
                                                  const float2* __restrict__ tbl) {
  __shared__ alignas(16) __bf16 At[2][128 * 32];
  __shared__ alignas(16) __bf16 Bt[2][128 * 32];
  const int K = 1024;
  const int tid = threadIdx.x, w = tid >> 6, l = tid & 63;
  const int l16 = l & 15, lq = l >> 4;
  const int wm = w >> 1, wn = w & 1;
  const int f = blockIdx.x;                 // 768 blocks
  const int swz = (f & 7) * 96 + (f >> 3);
  const int br = (swz / 24) * 128, bc = (swz % 24) * 128;
  f32x4 acc[4][4] = {};   // acc[n][m]
  const int off = w * 1024 + l * 16;
  const int rA = off >> 6, cA = off & 63;

  auto stage = [&](int bufi, int kt) {
    gload_lds16((const char*)A + ((size_t)(br + rA) * K + kt) * 2 + cA,
                (char*)(&At[bufi][0]) + w * 1024);
    gload_lds16((const char*)A + ((size_t)(br + 64 + rA) * K + kt) * 2 + cA,
                (char*)(&At[bufi][0]) + 4096 + w * 1024);
    gload_lds16((const char*)W + ((size_t)(bc + rA) * K + kt) * 2 + cA,
                (char*)(&Bt[bufi][0]) + w * 1024);
    gload_lds16((const char*)W + ((size_t)(bc + 64 + rA) * K + kt) * 2 + cA,
                (char*)(&Bt[bufi][0]) + 4096 + w * 1024);
  };

  stage(0, 0);
  VMCNT0();
  __builtin_amdgcn_s_barrier();

  int buf = 0;
  for (int i = 0; i < 32; ++i) {
    if (i + 1 < 32) stage(buf ^ 1, (i + 1) << 5);

    bf16x8 af[4], bfr[4];
#pragma unroll
    for (int m = 0; m < 4; ++m)
      af[m] = *(const bf16x8*)(&At[buf][0] + (wm * 64 + m * 16 + l16) * 32 + lq * 8);
#pragma unroll
    for (int n = 0; n < 4; ++n)
      bfr[n] = *(const bf16x8*)(&Bt[buf][0] + (wn * 64 + n * 16 + l16) * 32 + lq * 8);
    __builtin_amdgcn_s_setprio(1);
#pragma unroll
    for (int n = 0; n < 4; ++n)
#pragma unroll
      for (int m = 0; m < 4; ++m)
        acc[n][m] = __builtin_amdgcn_mfma_f32_16x16x32_bf16(bfr[n], af[m], acc[n][m], 0, 0, 0);
    __builtin_amdgcn_s_setprio(0);

    VMCNT0();
    __builtin_amdgcn_s_barrier();
    buf ^= 1;
  }

  const int sec = bc >> 10;        // 0=q, 1=k, 2=v — uniform per block
  const int cb = bc & 1023;
  if (sec == 2) {
#pragma unroll
    for (int n = 0; n < 4; ++n)
#pragma unroll
      for (int m = 0; m < 4; ++m) {
        int d0 = cb + wn * 64 + n * 16 + lq * 4;
        int h = d0 >> 6, dk = d0 & 63;
        int t = br + wm * 64 + m * 16 + l16;
        int b = t >> 11, tt = t & 2047;
#pragma unroll
        for (int r = 0; r < 4; ++r)
          vt[((size_t)((b * 16 + h) * 64 + dk + r)) * T_SEQ + tt] = (__bf16)acc[n][m][r];
      }
  } else {
    __bf16* dst = (sec == 0) ? qr : kr;
    const float sc = (sec == 0) ? 0.125f : 1.0f;   // fold 1/sqrt(64) into Q
#pragma unroll
    for (int n = 0; n < 4; ++n)
#pragma unroll
      for (int m = 0; m < 4; ++m) {
        int d0 = cb + wn * 64 + n * 16 + lq * 4;
        int h = d0 >> 6, dk = d0 & 63;
        int t = br + wm * 64 + m * 16 + l16;
        int b = t >> 11, tt = t & 2047;
        float2 cs0 = tbl[(dk >> 1) * T_SEQ + tt];        // [j][t]: coalesced
        float2 cs1 = tbl[((dk >> 1) + 1) * T_SEQ + tt];
        float v0 = acc[n][m][0], v1 = acc[n][m][1];
        float v2 = acc[n][m][2], v3 = acc[n][m][3];
        bf16x4 pk;
        pk[0] = (__bf16)((v0 * cs0.x - v1 * cs0.y) * sc);
        pk[1] = (__bf16)((v0 * cs0.y + v1 * cs0.x) * sc);
        pk[2] = (__bf16)((v2 * cs1.x - v3 * cs1.y) * sc);
        pk[3] = (__bf16)((v2 * cs1.y + v3 * cs1.x) * sc);
        *(bf16x4*)(dst + ((size_t)((b * 16 + h) * T_SEQ + tt)) * 64 + dk) = pk;
      }
  }
}

// ---------------- flash attention (swapped operands) ----------------
// 1D grid 1024, XCD swizzle: 4 heads per XCD (K/V fits L2), qb descending.
// 4 waves, wave owns 16 q rows (q = lane&15). In-lane softmax, defer-max.
__global__ __launch_bounds__(256) void attn_k(const __bf16* __restrict__ Qr,
                                              const __bf16* __restrict__ Kr,
                                              const __bf16* __restrict__ Vt,
                                              __bf16* __restrict__ out) {
  __shared__ alignas(16) __bf16 Kt[2][64 * 64];   // [key][d] rows 128B, swizzled
  __shared__ alignas(16) __bf16 Vtl[2][64 * 64];  // [d][key] rows 128B, swizzled
  __shared__ alignas(16) __bf16 Pt[4][16 * 64];   // per-wave P[q][key], swizzled
  const int f = blockIdx.x;
  const int swz = (f & 7) * 128 + (f >> 3);
  const int bh = swz >> 5;                 // 4 consecutive heads per XCD chunk
  const int qb0 = (31 - (swz & 31)) * 64;  // longest blocks first
  const int tid = threadIdx.x, w = tid >> 6, l = tid & 63;
  const int l16 = l & 15, lq = l >> 4;
  const int px = (l16 & 7) << 4;

  const __bf16* Qbase = Qr + ((size_t)bh * T_SEQ + qb0 + w * 16) * 64;
  bf16x8 aq0 = *(const bf16x8*)(Qbase + l16 * 64 + lq * 8);
  bf16x8 aq1 = *(const bf16x8*)(Qbase + l16 * 64 + 32 + lq * 8);

  float mrow = -1e30f, lrow = 0.0f;
  f32x4 acc[4] = {};   // acc[dt]: O^T[d=dt*16+lq*4+r][q=l16]

  const int nt = qb0 / 64 + 1;
  const int offbase = w * 1024 + l * 16;

  auto stage = [&](int bufi, int kt) {
#pragma unroll
    for (int c2 = 0; c2 < 2; ++c2) {
      int o = offbase + c2 * 4096;
      int row = o >> 7, cbyte = o & 127;
      int sw = cbyte ^ ((row & 7) << 4);   // pre-swizzled global source
      gload_lds16((const char*)Kr + ((size_t)(bh * T_SEQ + kt + row) * 64) * 2 + sw,
                  (char*)(&Kt[bufi][0]) + w * 1024 + c2 * 4096);
      gload_lds16((const char*)Vt + ((size_t)(bh * 64 + row) * T_SEQ + kt) * 2 + sw,
                  (char*)(&Vtl[bufi][0]) + w * 1024 + c2 * 4096);
    }
  };

  stage(0, 0);
  VMCNT0();
  __builtin_amdgcn_s_barrier();

  int buf = 0;
  for (int t = 0; t < nt; ++t) {
    const int kt = t * 64;
    if (t + 1 < nt) stage(buf ^ 1, kt + 64);   // prefetch overlaps compute

    const char* K0 = (const char*)&Kt[buf][0];
    const char* V0 = (const char*)&Vtl[buf][0];

    // S^T = K x Q^T : lane gets S[key=16g+lq*4+r][q=l16]
    f32x4 s[4] = {};
    __builtin_amdgcn_s_setprio(1);
#pragma unroll
    for (int g = 0; g < 4; ++g) {
      int row = g * 16 + l16;
      int x = (row & 7) << 4;
      bf16x8 k0 = *(const bf16x8*)(K0 + row * 128 + ((lq * 16) ^ x));
      s[g] = __builtin_amdgcn_mfma_f32_16x16x32_bf16(k0, aq0, s[g], 0, 0, 0);
      bf16x8 k1 = *(const bf16x8*)(K0 + row * 128 + ((lq * 16 + 64) ^ x));
      s[g] = __builtin_amdgcn_mfma_f32_16x16x32_bf16(k1, aq1, s[g], 0, 0, 0);
    }
    __builtin_amdgcn_s_setprio(0);

    if (t == nt - 1) {   // causal mask, diagonal tile only
      int q = qb0 + w * 16 + l16;
#pragma unroll
      for (int g = 0; g < 4; ++g)
#pragma unroll
        for (int r = 0; r < 4; ++r)
          if (kt + g * 16 + lq * 4 + r > q) s[g][r] = -1e30f;
    }

    float pm = -1e30f;
#pragma unroll
    for (int g = 0; g < 4; ++g)
#pragma unroll
      for (int r = 0; r < 4; ++r) pm = fmaxf(pm, s[g][r]);
    pm = fmaxf(pm, __shfl_xor(pm, 16));
    pm = fmaxf(pm, __shfl_xor(pm, 32));

    if (__any(pm > mrow + 8.0f)) {   // defer-max (T13)
      float mn = fmaxf(mrow, pm);
      float alpha = __expf(mrow - mn);
#pragma unroll
      for (int dt = 0; dt < 4; ++dt)
#pragma unroll
        for (int r = 0; r < 4; ++r) acc[dt][r] *= alpha;
      lrow *= alpha;
      mrow = mn;
    }

    char* Pw = (char*)&Pt[w][0] + l16 * 128;
    float rs = 0.0f;
#pragma unroll
    for (int g = 0; g < 4; ++g) {
      bf16x4 pk;
#pragma unroll
      for (int r = 0; r < 4; ++r) {
        float p = __expf(s[g][r] - mrow);
        rs += p;
        pk[r] = (__bf16)p;
      }
      *(bf16x4*)(Pw + ((g * 32 + lq * 8) ^ px)) = pk;
    }
    rs += __shfl_xor(rs, 16);
    rs += __shfl_xor(rs, 32);
    lrow += rs;

    // O^T += V^T x P^T
    __builtin_amdgcn_s_setprio(1);
#pragma unroll
    for (int ks = 0; ks < 2; ++ks) {
      bf16x8 ap = *(const bf16x8*)((const char*)&Pt[w][0] + l16 * 128 +
                                   ((ks * 64 + lq * 16) ^ px));
#pragma unroll
      for (int dt = 0; dt < 4; ++dt) {
        int vrow = dt * 16 + l16;
        bf16x8 vf = *(const bf16x8*)(V0 + vrow * 128 +
                                     ((ks * 64 + lq * 16) ^ ((vrow & 7) << 4)));
        acc[dt] = __builtin_amdgcn_mfma_f32_16x16x32_bf16(vf, ap, acc[dt], 0, 0, 0);
      }
    }
    __builtin_amdgcn_s_setprio(0);

    VMCNT0();
    __builtin_amdgcn_s_barrier();
    buf ^= 1;
  }

  // epilogue: out (B,T,H*64), lane holds 4 consecutive d per dt -> 8B stores
  const int b = bh >> 4, h = bh & 15;
  float inv = 1.0f / lrow;
  size_t row = (size_t)b * T_SEQ + qb0 + w * 16 + l16;
#pragma unroll
  for (int dt = 0; dt < 4; ++dt) {
    bf16x4 o;
#pragma unroll
    for (int r = 0; r < 4; ++r) o[r] = (__bf16)(acc[dt][r] * inv);
    *(bf16x4*)(out + row * DMODEL + h * 64 + dt * 16 + lq * 4) = o;
  }
}

extern "C" void kernel_launch(void* const* d_in, const int* in_sizes, int n_in,
                              void* d_out, int out_size, void* d_ws, size_t ws_size,
                              hipStream_t stream) {
  const float* x  = (const float*)d_in[0];
  const float* Wq = (const float*)d_in[1];
  const float* Wk = (const float*)d_in[2];
  const float* Wv = (const float*)d_in[3];
  const float* Wo = (const float*)d_in[4];
  const int* pos  = (const int*)d_in[5];

  char* ws = (char*)d_ws;
  __bf16* xb   = (__bf16*)(ws + 0);                // 8 MB (4096x1024)
  __bf16* wqkv = (__bf16*)(ws + (8u << 20));       // 6 MB (3072x1024)
  __bf16* wob  = (__bf16*)(ws + (14u << 20));      // 2 MB
  __bf16* qr   = (__bf16*)(ws + (16u << 20));      // 8 MB (B,H,T,64), pre-scaled 1/8
  __bf16* kr   = (__bf16*)(ws + (24u << 20));      // 8 MB (B,H,T,64)
  __bf16* vt   = (__bf16*)(ws + (32u << 20));      // 8 MB (B,H,64,T)
  __bf16* ao   = (__bf16*)(ws + (40u << 20));      // 8 MB (B,T,1024)
  float2* tbl  = (float2*)(ws + (48u << 20));      // 512 KB [j][t]

  f32_to_bf16_k<<<2048, 256, 0, stream>>>(x, xb, 4194304);
  w_to_bf16_k<<<2048, 256, 0, stream>>>(Wq, Wk, Wv, Wo, wqkv, wob);
  rope_table_k<<<256, 256, 0, stream>>>(pos, tbl);

  gemm_qkv_k<<<768, 256, 0, stream>>>(xb, wqkv, qr, kr, vt, tbl);

  attn_k<<<1024, 256, 0, stream>>>(qr, kr, vt, ao);

  gemm_bt<float><<<256, 256, 0, stream>>>(ao, wob, (float*)d_out, 4096, DMODEL, DMODEL);
}